// Round 8
// baseline (74.938 us; speedup 1.0000x reference)
//
#include <hip/hip_runtime.h>
#include <cstddef>
#include <cstdint>

// SelfAttention2d: B=8, C=64, N=4096, IC=8
// R8: R4 attn layout (VSTR=72, no swizzle) + double-buffered Vs with ONE
// barrier per 64-key tile (reg-staged write-after-barrier, loads 2 ahead).
// ns<=4 split-K, vectorized combine.

#define Bb 8
#define Cc 64
#define NN 4096
#define IC 8
#define VSTR 72      // LDS V row stride (bf16 elems) = 144B
#define XSTR 72      // LDS Xs row stride in P2

typedef __attribute__((ext_vector_type(8)))  short bf16x8;
typedef __attribute__((ext_vector_type(16))) float f32x16;
typedef unsigned short ushort_t;
typedef unsigned int   uint_t;

#define LOG2E 1.4426950408889634f

static __device__ __forceinline__ uint_t f2bf(float x) {   // RNE
    union { float f; uint_t u; } v; v.f = x;
    uint_t r = v.u + 0x7FFF + ((v.u >> 16) & 1);
    return r >> 16;
}
static __device__ __forceinline__ float bitsf(uint_t u) {
    union { uint_t u; float f; } v; v.u = u; return v.f;
}
static __device__ __forceinline__ float fexp2(float x) {
#if __has_builtin(__builtin_amdgcn_exp2f)
    return __builtin_amdgcn_exp2f(x);
#else
    return exp2f(x);
#endif
}
static __device__ __forceinline__ uint_t fbits(float x) {
    union { float f; uint_t u; } v; v.f = x; return v.u;
}
// pack (lo=even, hi=odd) truncated bf16 pair via v_perm
static __device__ __forceinline__ uint_t packbf(float e, float o) {
#if __has_builtin(__builtin_amdgcn_perm)
    return __builtin_amdgcn_perm(fbits(o), fbits(e), 0x07060302u);
#else
    return (fbits(e) >> 16) | (fbits(o) & 0xFFFF0000u);
#endif
}

union U4B { uint4 u; bf16x8 v; };

// ---------------- P1: transpose x -> xbf [b][n][c] bf16; block 512: weights ----
__global__ __launch_bounds__(256) void p1_kernel(
    const float* __restrict__ x,
    const float* __restrict__ theta_w, const float* __restrict__ theta_b,
    const float* __restrict__ phi_w,   const float* __restrict__ phi_b,
    const float* __restrict__ g_w,     const float* __restrict__ g_b,
    ushort_t* __restrict__ xbf, ushort_t* __restrict__ Wbf, float* __restrict__ biasf)
{
    const int t = threadIdx.x;
    const int bid = blockIdx.x;
    if (bid < 512) {
        __shared__ float Xt[64 * 68];
        const int b  = bid >> 6;
        const int nt = (bid & 63) * 64;
        const int c = t >> 2, nsg = t & 3;
        const float* xs = x + ((size_t)(b * 64 + c)) * NN + nt + nsg * 16;
        #pragma unroll
        for (int i = 0; i < 4; i++) {
            float4 v = ((const float4*)xs)[i];
            *(float4*)(Xt + c * 68 + nsg * 16 + i * 4) = v;
        }
        __syncthreads();
        const int n = t & 63, cs = t >> 6;
        uint_t wv[8];
        #pragma unroll
        for (int i = 0; i < 8; i++) {
            float e0 = Xt[(cs * 16 + 2 * i + 0) * 68 + n];
            float e1 = Xt[(cs * 16 + 2 * i + 1) * 68 + n];
            wv[i] = f2bf(e0) | (f2bf(e1) << 16);
        }
        ushort_t* dst = xbf + ((size_t)(b * NN + nt + n)) * 64 + cs * 16;
        *(uint4*)dst       = make_uint4(wv[0], wv[1], wv[2], wv[3]);
        *(uint4*)(dst + 8) = make_uint4(wv[4], wv[5], wv[6], wv[7]);
    } else {
        // weights: Wbf[96][64] = [g(0-63); theta*log2e(64-71); phi(72-79); zero]
        for (int i = t; i < 96 * 64; i += 256) {
            int row = i >> 6, c = i & 63;
            float v;
            if (row < 64)      v = g_w[row * 64 + c];
            else if (row < 72) v = theta_w[(row - 64) * 64 + c] * LOG2E;
            else if (row < 80) v = phi_w[(row - 72) * 64 + c];
            else               v = 0.0f;
            Wbf[i] = (ushort_t)f2bf(v);
        }
        if (t < 96) {
            float bv = (t < 64) ? g_b[t]
                     : (t < 72) ? theta_b[t - 64] * LOG2E
                     : (t < 80) ? phi_b[t - 72] : 0.0f;
            biasf[t] = bv;
        }
    }
}

// ---------------- P2: projection GEMM: Y[96 x 128n] = W * X  per block ----------
__global__ __launch_bounds__(256) void p2_kernel(
    const ushort_t* __restrict__ xbf, const ushort_t* __restrict__ Wbf,
    const float* __restrict__ biasf,
    ushort_t* __restrict__ Qw, ushort_t* __restrict__ Kw, ushort_t* __restrict__ Vt)
{
    __shared__ ushort_t Xs[128 * XSTR];
    __shared__ float bs[96];

    const int t = threadIdx.x;
    const int lane = t & 63, w = t >> 6;
    const int l31 = lane & 31, hi = lane >> 5;
    const int b  = blockIdx.x >> 5;
    const int n0 = (blockIdx.x & 31) * 128;

    {
        const int n = t >> 1, h = t & 1;
        const ushort_t* src = xbf + ((size_t)(b * NN + n0 + n)) * 64 + h * 32;
        #pragma unroll
        for (int i = 0; i < 4; i++) {
            uint4 v = ((const uint4*)src)[i];
            *(uint4*)(Xs + n * XSTR + h * 32 + i * 8) = v;
        }
    }
    if (t < 96) bs[t] = biasf[t];
    __syncthreads();

    bf16x8 af[3][4];
    #pragma unroll
    for (int mt = 0; mt < 3; mt++)
        #pragma unroll
        for (int kc = 0; kc < 4; kc++)
            af[mt][kc] = *(const bf16x8*)(Wbf + (size_t)(mt * 32 + l31) * 64 + kc * 16 + hi * 8);

    f32x16 ac0 = {}, ac1 = {}, ac2 = {};
    #pragma unroll
    for (int kc = 0; kc < 4; kc++) {
        bf16x8 bv = *(const bf16x8*)(Xs + (w * 32 + l31) * XSTR + kc * 16 + hi * 8);
        ac0 = __builtin_amdgcn_mfma_f32_32x32x16_bf16(af[0][kc], bv, ac0, 0, 0, 0);
        ac1 = __builtin_amdgcn_mfma_f32_32x32x16_bf16(af[1][kc], bv, ac1, 0, 0, 0);
        ac2 = __builtin_amdgcn_mfma_f32_32x32x16_bf16(af[2][kc], bv, ac2, 0, 0, 0);
    }

    const int nw = n0 + w * 32;
    const int sig = ((l31 >> 3) & 1) * 16 + ((l31 >> 2) & 1) * 8 + ((l31 >> 4) & 1) * 4 + (l31 & 3);

    #pragma unroll
    for (int reg = 0; reg < 16; reg++) {
        int m = reg >> 2, r = reg & 3;
        {
            int ch = 4 * hi + 8 * m + r;
            float val = ac0[reg] + bs[ch];
            Vt[((size_t)(b * 64 + ch)) * NN + nw + sig] = (ushort_t)f2bf(val);
        }
        {
            int ch = 32 + 4 * hi + 8 * m + r;
            float val = ac1[reg] + bs[ch];
            Vt[((size_t)(b * 64 + ch)) * NN + nw + sig] = (ushort_t)f2bf(val);
        }
    }
    {
        float q0 = ac2[0] + bs[64 + 4 * hi + 0];
        float q1 = ac2[1] + bs[64 + 4 * hi + 1];
        float q2 = ac2[2] + bs[64 + 4 * hi + 2];
        float q3 = ac2[3] + bs[64 + 4 * hi + 3];
        uint2 qp = make_uint2(f2bf(q0) | (f2bf(q1) << 16), f2bf(q2) | (f2bf(q3) << 16));
        *(uint2*)(Qw + ((size_t)(b * NN) + nw + l31) * 8 + hi * 4) = qp;
        float p0 = ac2[4] + bs[72 + 4 * hi + 0];
        float p1 = ac2[5] + bs[72 + 4 * hi + 1];
        float p2 = ac2[6] + bs[72 + 4 * hi + 2];
        float p3 = ac2[7] + bs[72 + 4 * hi + 3];
        uint2 kp = make_uint2(f2bf(p0) | (f2bf(p1) << 16), f2bf(p2) | (f2bf(p3) << 16));
        *(uint2*)(Kw + ((size_t)(b * NN) + nw + l31) * 8 + hi * 4) = kp;
    }
}

// ---------------- attention: 32x32x16, m==0 softmax, register P ----------------
// R4 layout; Vs double-buffered, ONE barrier per tile.
template <int FIN>
__global__ __launch_bounds__(256) void attn_kernel(
    const ushort_t* __restrict__ Qw, const ushort_t* __restrict__ Kw,
    const ushort_t* __restrict__ Vt,
    ushort_t* __restrict__ P, float* __restrict__ L, int nsplit,
    const float* __restrict__ x, const float* __restrict__ gamma,
    float* __restrict__ out)
{
    __shared__ ushort_t Vs[2][64 * VSTR];   // 18432 B

    const int t = threadIdx.x;
    const int lane = t & 63, w = t >> 6;
    const int l31 = lane & 31, hi = lane >> 5;

    int bid = blockIdx.x;
    const int qt = bid & 31;
    const int b  = (bid >> 5) & 7;
    const int s  = bid >> 8;
    const int q0 = qt * 128 + w * 32;
    const int keys = NN / nsplit;
    const int k0 = s * keys;
    const int ntiles = keys / 64;

    const ushort_t* Kb = Kw + (size_t)b * NN * 8;
    const ushort_t* Vb = Vt + (size_t)b * 64 * NN;

    bf16x8 qf = {};
    if (hi == 0)
        qf = *(const bf16x8*)(Qw + ((size_t)b * NN + q0 + l31) * 8);

    const int vch = t >> 2, vsg = t & 3;
    const ushort_t* vsrc = Vb + (size_t)vch * NN + k0 + vsg * 16;
    const int ws0 = vch * VSTR + vsg * 16;
    const int ws1 = ws0 + 8;

    // ---- prologue: tile 0 -> Vs[0]; stage tile 1 in regs ----
    {
        uint4 a0 = *(const uint4*)(vsrc);
        uint4 a1 = *(const uint4*)(vsrc + 8);
        *(uint4*)(Vs[0] + ws0) = a0;
        *(uint4*)(Vs[0] + ws1) = a1;
    }
    uint4 kc0 = {}, kc1 = {};
    if (hi == 0) {
        kc0 = *(const uint4*)(Kb + (size_t)(k0 + l31) * 8);
        kc1 = *(const uint4*)(Kb + (size_t)(k0 + 32 + l31) * 8);
    }
    uint4 vn0 = {}, vn1 = {}, kn0 = {}, kn1 = {};
    if (ntiles > 1) {
        vn0 = *(const uint4*)(vsrc + 64);
        vn1 = *(const uint4*)(vsrc + 64 + 8);
        if (hi == 0) {
            kn0 = *(const uint4*)(Kb + (size_t)(k0 + 64 + l31) * 8);
            kn1 = *(const uint4*)(Kb + (size_t)(k0 + 64 + 32 + l31) * 8);
        }
    }
    __syncthreads();

    f32x16 acc0 = {}, acc1 = {};
    float lsum = 0.0f;
    const f32x16 zf = {};

    for (int tt = 0; tt < ntiles; ++tt) {
        const int cur = tt & 1;
        // write staged tile t+1 into the other buffer (no barrier needed:
        // everyone finished reading it at end of tile t-1)
        if (tt + 1 < ntiles) {
            *(uint4*)(Vs[cur ^ 1] + ws0) = vn0;
            *(uint4*)(Vs[cur ^ 1] + ws1) = vn1;
        }
        // issue tile t+2 V loads (regs free after ds_write issue)
        if (tt + 2 < ntiles) {
            const ushort_t* v2 = vsrc + (size_t)(tt + 2) * 64;
            vn0 = *(const uint4*)(v2);
            vn1 = *(const uint4*)(v2 + 8);
        }

        // ---- compute tile tt from Vs[cur], K from regs ----
        U4B ka0, ka1; ka0.u = kc0; ka1.u = kc1;
        f32x16 S0 = __builtin_amdgcn_mfma_f32_32x32x16_bf16(ka0.v, qf, zf, 0, 0, 0);
        f32x16 S1 = __builtin_amdgcn_mfma_f32_32x32x16_bf16(ka1.v, qf, zf, 0, 0, 0);

        float p0[16], p1[16];
        #pragma unroll
        for (int i = 0; i < 16; i++) { p0[i] = fexp2(S0[i]); }
        #pragma unroll
        for (int i = 0; i < 16; i++) { p1[i] = fexp2(S1[i]); }
        #pragma unroll
        for (int i = 0; i < 16; i++) { lsum += p0[i]; lsum += p1[i]; }

        uint_t pk0[8], pk1[8];
        #pragma unroll
        for (int m = 0; m < 4; m++) {
            #pragma unroll
            for (int rp = 0; rp < 2; rp++) {
                pk0[m * 2 + rp] = packbf(p0[m * 4 + 2 * rp], p0[m * 4 + 2 * rp + 1]);
                pk1[m * 2 + rp] = packbf(p1[m * 4 + 2 * rp], p1[m * 4 + 2 * rp + 1]);
            }
        }

        #pragma unroll
        for (int kf = 0; kf < 2; kf++) {
            #pragma unroll
            for (int c = 0; c < 2; c++) {
                U4B bu;
                if (kf == 0) bu.u = make_uint4(pk0[c * 2], pk0[c * 2 + 1], pk0[(c + 2) * 2], pk0[(c + 2) * 2 + 1]);
                else         bu.u = make_uint4(pk1[c * 2], pk1[c * 2 + 1], pk1[(c + 2) * 2], pk1[(c + 2) * 2 + 1]);
                bf16x8 av0 = *(const bf16x8*)(Vs[cur] + (0 * 32 + l31) * VSTR + kf * 32 + c * 16 + hi * 8);
                bf16x8 av1 = *(const bf16x8*)(Vs[cur] + (1 * 32 + l31) * VSTR + kf * 32 + c * 16 + hi * 8);
                acc0 = __builtin_amdgcn_mfma_f32_32x32x16_bf16(av0, bu.v, acc0, 0, 0, 0);
                acc1 = __builtin_amdgcn_mfma_f32_32x32x16_bf16(av1, bu.v, acc1, 0, 0, 0);
            }
        }

        // rotate K regs; issue t+2 K loads
        kc0 = kn0; kc1 = kn1;
        if (tt + 2 < ntiles && hi == 0) {
            const ushort_t* kk2 = Kb + (size_t)(k0 + (tt + 2) * 64) * 8;
            kn0 = *(const uint4*)(kk2 + (size_t)l31 * 8);
            kn1 = *(const uint4*)(kk2 + (size_t)(32 + l31) * 8);
        }
        // single barrier: publishes Vs[cur^1] writes, ends reads of Vs[cur]
        __syncthreads();
    }

    float ltot = lsum + __shfl_xor(lsum, 32);

    if (!FIN) {
        ushort_t* Pb = P + ((size_t)(s * Bb + b) * 64) * NN;
        #pragma unroll
        for (int reg = 0; reg < 16; reg++) {
            int m = reg >> 2, r = reg & 3;
            int ch0 = 4 * hi + 8 * m + r;
            Pb[(size_t)ch0 * NN + q0 + l31]        = (ushort_t)f2bf(acc0[reg]);
            Pb[(size_t)(ch0 + 32) * NN + q0 + l31] = (ushort_t)f2bf(acc1[reg]);
        }
        if (lane < 32)
            L[(size_t)(s * Bb + b) * NN + q0 + lane] = ltot;
    } else {
        const float gm = gamma[0];
        const float inv = 1.0f / ltot;
        #pragma unroll
        for (int reg = 0; reg < 16; reg++) {
            int m = reg >> 2, r = reg & 3;
            int ch0 = 4 * hi + 8 * m + r;
            size_t i0 = ((size_t)(b * 64 + ch0)) * NN + q0 + l31;
            size_t i1 = ((size_t)(b * 64 + ch0 + 32)) * NN + q0 + l31;
            out[i0] = x[i0] + gm * acc0[reg] * inv;
            out[i1] = x[i1] + gm * acc1[reg] * inv;
        }
    }
}

// ---------------- combine: thread = 8q x 8ch, vectorized ----------------------
__global__ __launch_bounds__(128) void combine_kernel(
    const ushort_t* __restrict__ P, const float* __restrict__ L,
    const float* __restrict__ x, const float* __restrict__ gamma,
    float* __restrict__ out, int nsplit)
{
    const int g = blockIdx.x * 128 + threadIdx.x;   // 32768 threads
    const int qo = g & 511;
    const int q0 = qo * 8;
    const int rest = g >> 9;                         // 0..63
    const int b  = rest & 7;
    const int cg = rest >> 3;                        // 0..7 -> ch0 = cg*8

    float ls[8];
    #pragma unroll
    for (int j = 0; j < 8; j++) ls[j] = 0.f;
    for (int s = 0; s < nsplit; s++) {
        const float* Lb = L + (size_t)(s * Bb + b) * NN + q0;
        float4 l0 = *(const float4*)(Lb);
        float4 l1 = *(const float4*)(Lb + 4);
        ls[0] += l0.x; ls[1] += l0.y; ls[2] += l0.z; ls[3] += l0.w;
        ls[4] += l1.x; ls[5] += l1.y; ls[6] += l1.z; ls[7] += l1.w;
    }

    float a[8][8];
    #pragma unroll
    for (int j = 0; j < 8; j++)
        #pragma unroll
        for (int k = 0; k < 8; k++) a[j][k] = 0.f;

    for (int s = 0; s < nsplit; s++) {
        #pragma unroll
        for (int j = 0; j < 8; j++) {
            const ushort_t* Pr = P + ((size_t)(s * Bb + b) * 64 + cg * 8 + j) * NN + q0;
            uint4 pv = *(const uint4*)Pr;
            uint_t u0 = pv.x, u1 = pv.y, u2 = pv.z, u3 = pv.w;
            a[j][0] += bitsf(u0 << 16); a[j][1] += bitsf(u0 & 0xFFFF0000u);
            a[j][2] += bitsf(u1 << 16); a[j][3] += bitsf(u1 & 0xFFFF0000u);
            a[j][4] += bitsf(u2 << 16); a[j][5] += bitsf(u2 & 0xFFFF0000u);
            a[j][6] += bitsf(u3 << 16); a[j][7] += bitsf(u3 & 0xFFFF0000u);
        }
    }

    float inv[8];
    #pragma unroll
    for (int k = 0; k < 8; k++) inv[k] = 1.0f / ls[k];
    const float gm = gamma[0];

    #pragma unroll
    for (int j = 0; j < 8; j++) {
        const size_t ro = ((size_t)(b * 64 + cg * 8 + j)) * NN + q0;
        float4 x0 = *(const float4*)(x + ro);
        float4 x1 = *(const float4*)(x + ro + 4);
        float4 o0, o1;
        o0.x = x0.x + gm * a[j][0] * inv[0];
        o0.y = x0.y + gm * a[j][1] * inv[1];
        o0.z = x0.z + gm * a[j][2] * inv[2];
        o0.w = x0.w + gm * a[j][3] * inv[3];
        o1.x = x1.x + gm * a[j][4] * inv[4];
        o1.y = x1.y + gm * a[j][5] * inv[5];
        o1.z = x1.z + gm * a[j][6] * inv[6];
        o1.w = x1.w + gm * a[j][7] * inv[7];
        *(float4*)(out + ro)     = o0;
        *(float4*)(out + ro + 4) = o1;
    }
}

extern "C" void kernel_launch(void* const* d_in, const int* in_sizes, int n_in,
                              void* d_out, int out_size, void* d_ws, size_t ws_size,
                              hipStream_t stream)
{
    const float* x       = (const float*)d_in[0];
    const float* theta_w = (const float*)d_in[1];
    const float* theta_b = (const float*)d_in[2];
    const float* phi_w   = (const float*)d_in[3];
    const float* phi_b   = (const float*)d_in[4];
    const float* g_w     = (const float*)d_in[5];
    const float* g_b     = (const float*)d_in[6];
    const float* gamma   = (const float*)d_in[7];
    float* out = (float*)d_out;

    // ws carve (all 16B aligned)
    char* p = (char*)d_ws;
    ushort_t* Qw  = (ushort_t*)p;  p += (size_t)Bb * NN * 8 * 2;        // 512 KB
    ushort_t* Kw  = (ushort_t*)p;  p += (size_t)Bb * NN * 8 * 2;        // 512 KB
    ushort_t* Vt  = (ushort_t*)p;  p += (size_t)Bb * 64 * NN * 2;       // 4 MB
    ushort_t* xbf = (ushort_t*)p;  p += (size_t)Bb * NN * 64 * 2;       // 4 MB
    ushort_t* Wbf = (ushort_t*)p;  p += 96 * 64 * 2;                    // 12 KB
    float*    biasf = (float*)p;   p += 96 * 4 + 128;                   // pad
    char*     pbase = p;
    const size_t base_bytes  = (size_t)(pbase - (char*)d_ws);
    const size_t split_bytes = (size_t)Bb * 64 * NN * 2 + (size_t)Bb * NN * 4;

    int ns = 1;
    const int cands[3] = {4, 2, 1};
    for (int i = 0; i < 3; i++)
        if (base_bytes + (size_t)cands[i] * split_bytes <= ws_size) { ns = cands[i]; break; }

    ushort_t* P = (ushort_t*)pbase;
    float*    L = (float*)(pbase + (size_t)ns * Bb * 64 * NN * 2);

    p1_kernel<<<513, 256, 0, stream>>>(x, theta_w, theta_b, phi_w, phi_b, g_w, g_b,
                                       xbf, Wbf, biasf);
    p2_kernel<<<Bb * 32, 256, 0, stream>>>(xbf, Wbf, biasf, Qw, Kw, Vt);

    if (ns > 1) {
        attn_kernel<0><<<ns * Bb * 32, 256, 0, stream>>>(Qw, Kw, Vt, P, L, ns,
                                                         nullptr, nullptr, nullptr);
        combine_kernel<<<256, 128, 0, stream>>>(P, L, x, gamma, out, ns);
    } else {
        attn_kernel<1><<<Bb * 32, 256, 0, stream>>>(Qw, Kw, Vt, P, L, 1,
                                                    x, gamma, out);
    }
}

// Round 9
// 65.176 us; speedup vs baseline: 1.1498x; 1.1498x over previous
//
#include <hip/hip_runtime.h>
#include <cstddef>
#include <cstdint>

// SelfAttention2d: B=8, C=64, N=4096, IC=8
// R9: R4 math/layout (VSTR=72, conflict-free). Attn restructured:
//  - 8 waves/block (256 q rows), grid 512 @ ns=4, XCD-aware bid (b = bid&7)
//  - raw s_barrier + explicit lgkmcnt(0) (no vmcnt drain at barriers)
//  - static A/B prefetch sets, V issued 1 tile ahead of ds_write, K 2 ahead

#define Bb 8
#define Cc 64
#define NN 4096
#define IC 8
#define VSTR 72      // LDS V row stride (bf16 elems) = 144B
#define XSTR 72      // LDS Xs row stride in P2

typedef __attribute__((ext_vector_type(8)))  short bf16x8;
typedef __attribute__((ext_vector_type(16))) float f32x16;
typedef unsigned short ushort_t;
typedef unsigned int   uint_t;

#define LOG2E 1.4426950408889634f

static __device__ __forceinline__ uint_t f2bf(float x) {   // RNE
    union { float f; uint_t u; } v; v.f = x;
    uint_t r = v.u + 0x7FFF + ((v.u >> 16) & 1);
    return r >> 16;
}
static __device__ __forceinline__ float bitsf(uint_t u) {
    union { uint_t u; float f; } v; v.u = u; return v.f;
}
static __device__ __forceinline__ float fexp2(float x) {
#if __has_builtin(__builtin_amdgcn_exp2f)
    return __builtin_amdgcn_exp2f(x);
#else
    return exp2f(x);
#endif
}
static __device__ __forceinline__ uint_t fbits(float x) {
    union { float f; uint_t u; } v; v.f = x; return v.u;
}
// pack (lo=even, hi=odd) truncated bf16 pair via v_perm
static __device__ __forceinline__ uint_t packbf(float e, float o) {
#if __has_builtin(__builtin_amdgcn_perm)
    return __builtin_amdgcn_perm(fbits(o), fbits(e), 0x07060302u);
#else
    return (fbits(e) >> 16) | (fbits(o) & 0xFFFF0000u);
#endif
}

union U4B { uint4 u; bf16x8 v; };

// ---------------- P1: transpose x -> xbf [b][n][c] bf16; block 512: weights ----
__global__ __launch_bounds__(256) void p1_kernel(
    const float* __restrict__ x,
    const float* __restrict__ theta_w, const float* __restrict__ theta_b,
    const float* __restrict__ phi_w,   const float* __restrict__ phi_b,
    const float* __restrict__ g_w,     const float* __restrict__ g_b,
    ushort_t* __restrict__ xbf, ushort_t* __restrict__ Wbf, float* __restrict__ biasf)
{
    const int t = threadIdx.x;
    const int bid = blockIdx.x;
    if (bid < 512) {
        __shared__ float Xt[64 * 68];
        const int b  = bid >> 6;
        const int nt = (bid & 63) * 64;
        const int c = t >> 2, nsg = t & 3;
        const float* xs = x + ((size_t)(b * 64 + c)) * NN + nt + nsg * 16;
        #pragma unroll
        for (int i = 0; i < 4; i++) {
            float4 v = ((const float4*)xs)[i];
            *(float4*)(Xt + c * 68 + nsg * 16 + i * 4) = v;
        }
        __syncthreads();
        const int n = t & 63, cs = t >> 6;
        uint_t wv[8];
        #pragma unroll
        for (int i = 0; i < 8; i++) {
            float e0 = Xt[(cs * 16 + 2 * i + 0) * 68 + n];
            float e1 = Xt[(cs * 16 + 2 * i + 1) * 68 + n];
            wv[i] = f2bf(e0) | (f2bf(e1) << 16);
        }
        ushort_t* dst = xbf + ((size_t)(b * NN + nt + n)) * 64 + cs * 16;
        *(uint4*)dst       = make_uint4(wv[0], wv[1], wv[2], wv[3]);
        *(uint4*)(dst + 8) = make_uint4(wv[4], wv[5], wv[6], wv[7]);
    } else {
        // weights: Wbf[96][64] = [g(0-63); theta*log2e(64-71); phi(72-79); zero]
        for (int i = t; i < 96 * 64; i += 256) {
            int row = i >> 6, c = i & 63;
            float v;
            if (row < 64)      v = g_w[row * 64 + c];
            else if (row < 72) v = theta_w[(row - 64) * 64 + c] * LOG2E;
            else if (row < 80) v = phi_w[(row - 72) * 64 + c];
            else               v = 0.0f;
            Wbf[i] = (ushort_t)f2bf(v);
        }
        if (t < 96) {
            float bv = (t < 64) ? g_b[t]
                     : (t < 72) ? theta_b[t - 64] * LOG2E
                     : (t < 80) ? phi_b[t - 72] : 0.0f;
            biasf[t] = bv;
        }
    }
}

// ---------------- P2: projection GEMM: Y[96 x 128n] = W * X  per block ----------
__global__ __launch_bounds__(256) void p2_kernel(
    const ushort_t* __restrict__ xbf, const ushort_t* __restrict__ Wbf,
    const float* __restrict__ biasf,
    ushort_t* __restrict__ Qw, ushort_t* __restrict__ Kw, ushort_t* __restrict__ Vt)
{
    __shared__ ushort_t Xs[128 * XSTR];
    __shared__ float bs[96];

    const int t = threadIdx.x;
    const int lane = t & 63, w = t >> 6;
    const int l31 = lane & 31, hi = lane >> 5;
    const int b  = blockIdx.x >> 5;
    const int n0 = (blockIdx.x & 31) * 128;

    {
        const int n = t >> 1, h = t & 1;
        const ushort_t* src = xbf + ((size_t)(b * NN + n0 + n)) * 64 + h * 32;
        #pragma unroll
        for (int i = 0; i < 4; i++) {
            uint4 v = ((const uint4*)src)[i];
            *(uint4*)(Xs + n * XSTR + h * 32 + i * 8) = v;
        }
    }
    if (t < 96) bs[t] = biasf[t];
    __syncthreads();

    bf16x8 af[3][4];
    #pragma unroll
    for (int mt = 0; mt < 3; mt++)
        #pragma unroll
        for (int kc = 0; kc < 4; kc++)
            af[mt][kc] = *(const bf16x8*)(Wbf + (size_t)(mt * 32 + l31) * 64 + kc * 16 + hi * 8);

    f32x16 ac0 = {}, ac1 = {}, ac2 = {};
    #pragma unroll
    for (int kc = 0; kc < 4; kc++) {
        bf16x8 bv = *(const bf16x8*)(Xs + (w * 32 + l31) * XSTR + kc * 16 + hi * 8);
        ac0 = __builtin_amdgcn_mfma_f32_32x32x16_bf16(af[0][kc], bv, ac0, 0, 0, 0);
        ac1 = __builtin_amdgcn_mfma_f32_32x32x16_bf16(af[1][kc], bv, ac1, 0, 0, 0);
        ac2 = __builtin_amdgcn_mfma_f32_32x32x16_bf16(af[2][kc], bv, ac2, 0, 0, 0);
    }

    const int nw = n0 + w * 32;
    const int sig = ((l31 >> 3) & 1) * 16 + ((l31 >> 2) & 1) * 8 + ((l31 >> 4) & 1) * 4 + (l31 & 3);

    #pragma unroll
    for (int reg = 0; reg < 16; reg++) {
        int m = reg >> 2, r = reg & 3;
        {
            int ch = 4 * hi + 8 * m + r;
            float val = ac0[reg] + bs[ch];
            Vt[((size_t)(b * 64 + ch)) * NN + nw + sig] = (ushort_t)f2bf(val);
        }
        {
            int ch = 32 + 4 * hi + 8 * m + r;
            float val = ac1[reg] + bs[ch];
            Vt[((size_t)(b * 64 + ch)) * NN + nw + sig] = (ushort_t)f2bf(val);
        }
    }
    {
        float q0 = ac2[0] + bs[64 + 4 * hi + 0];
        float q1 = ac2[1] + bs[64 + 4 * hi + 1];
        float q2 = ac2[2] + bs[64 + 4 * hi + 2];
        float q3 = ac2[3] + bs[64 + 4 * hi + 3];
        uint2 qp = make_uint2(f2bf(q0) | (f2bf(q1) << 16), f2bf(q2) | (f2bf(q3) << 16));
        *(uint2*)(Qw + ((size_t)(b * NN) + nw + l31) * 8 + hi * 4) = qp;
        float p0 = ac2[4] + bs[72 + 4 * hi + 0];
        float p1 = ac2[5] + bs[72 + 4 * hi + 1];
        float p2 = ac2[6] + bs[72 + 4 * hi + 2];
        float p3 = ac2[7] + bs[72 + 4 * hi + 3];
        uint2 kp = make_uint2(f2bf(p0) | (f2bf(p1) << 16), f2bf(p2) | (f2bf(p3) << 16));
        *(uint2*)(Kw + ((size_t)(b * NN) + nw + l31) * 8 + hi * 4) = kp;
    }
}

// one 64-key tile of flash attn (R4 math, verbatim)
#define COMPUTE_TILE(CURBUF, KC0, KC1)                                                    \
    {                                                                                     \
        U4B ka0_, ka1_; ka0_.u = KC0; ka1_.u = KC1;                                       \
        f32x16 S0 = __builtin_amdgcn_mfma_f32_32x32x16_bf16(ka0_.v, qf, zf, 0, 0, 0);     \
        f32x16 S1 = __builtin_amdgcn_mfma_f32_32x32x16_bf16(ka1_.v, qf, zf, 0, 0, 0);     \
        float p0[16], p1[16];                                                             \
        _Pragma("unroll") for (int i = 0; i < 16; i++) p0[i] = fexp2(S0[i]);              \
        _Pragma("unroll") for (int i = 0; i < 16; i++) p1[i] = fexp2(S1[i]);              \
        _Pragma("unroll") for (int i = 0; i < 16; i++) { lsum += p0[i]; lsum += p1[i]; }  \
        uint_t pk0[8], pk1[8];                                                            \
        _Pragma("unroll") for (int m = 0; m < 4; m++) {                                   \
            _Pragma("unroll") for (int rp = 0; rp < 2; rp++) {                            \
                pk0[m * 2 + rp] = packbf(p0[m * 4 + 2 * rp], p0[m * 4 + 2 * rp + 1]);     \
                pk1[m * 2 + rp] = packbf(p1[m * 4 + 2 * rp], p1[m * 4 + 2 * rp + 1]);     \
            }                                                                             \
        }                                                                                 \
        _Pragma("unroll") for (int kf = 0; kf < 2; kf++) {                                \
            _Pragma("unroll") for (int c = 0; c < 2; c++) {                               \
                U4B bu;                                                                   \
                if (kf == 0) bu.u = make_uint4(pk0[c * 2], pk0[c * 2 + 1],                \
                                               pk0[(c + 2) * 2], pk0[(c + 2) * 2 + 1]);  \
                else         bu.u = make_uint4(pk1[c * 2], pk1[c * 2 + 1],                \
                                               pk1[(c + 2) * 2], pk1[(c + 2) * 2 + 1]);  \
                bf16x8 av0 = *(const bf16x8*)(Vs[CURBUF] + (0 * 32 + l31) * VSTR + kf * 32 + c * 16 + hi * 8); \
                bf16x8 av1 = *(const bf16x8*)(Vs[CURBUF] + (1 * 32 + l31) * VSTR + kf * 32 + c * 16 + hi * 8); \
                acc0 = __builtin_amdgcn_mfma_f32_32x32x16_bf16(av0, bu.v, acc0, 0, 0, 0); \
                acc1 = __builtin_amdgcn_mfma_f32_32x32x16_bf16(av1, bu.v, acc1, 0, 0, 0); \
            }                                                                             \
        }                                                                                 \
    }

// ---------------- attention: 8 waves, raw barriers, A/B prefetch sets ----------
template <int FIN>
__global__ __launch_bounds__(512, 3) void attn_kernel(
    const ushort_t* __restrict__ Qw, const ushort_t* __restrict__ Kw,
    const ushort_t* __restrict__ Vt,
    ushort_t* __restrict__ P, float* __restrict__ L, int nsplit,
    const float* __restrict__ x, const float* __restrict__ gamma,
    float* __restrict__ out)
{
    __shared__ ushort_t Vs[2][64 * VSTR];   // 18432 B

    const int t = threadIdx.x;
    const int lane = t & 63, w = t >> 6;          // 8 waves
    const int l31 = lane & 31, hi = lane >> 5;

    int bid = blockIdx.x;
    const int b  = bid & 7;                        // XCD-aligned batch
    const int qt = (bid >> 3) & 15;
    const int s  = bid >> 7;
    const int q0 = qt * 256 + w * 32;
    const int keys = NN / nsplit;
    const int k0 = s * keys;
    const int ntiles = keys / 64;                  // even for ns in {1,2,4}

    const ushort_t* Kb = Kw + (size_t)b * NN * 8;
    const ushort_t* Vb = Vt + (size_t)b * 64 * NN;

    bf16x8 qf = {};
    if (hi == 0)
        qf = *(const bf16x8*)(Qw + ((size_t)b * NN + q0 + l31) * 8);

    // V staging: 512 threads x 16B = 8KB tile
    const int vch = t >> 3, vsg = t & 7;
    const ushort_t* vsrc = Vb + (size_t)vch * NN + k0 + vsg * 8;
    const int ws = vch * VSTR + vsg * 8;

    uint4 vA, vB;
    uint4 kA0 = {}, kA1 = {}, kB0 = {}, kB1 = {};

    // prologue: tile 0 -> Vs[0]; then issue tile-1 loads (after the full drain)
    vA = *(const uint4*)(vsrc);
    if (hi == 0) {
        kA0 = *(const uint4*)(Kb + (size_t)(k0 + l31) * 8);
        kA1 = *(const uint4*)(Kb + (size_t)(k0 + 32 + l31) * 8);
    }
    *(uint4*)(Vs[0] + ws) = vA;
    __syncthreads();
    vB = *(const uint4*)(vsrc + 64);
    if (hi == 0) {
        kB0 = *(const uint4*)(Kb + (size_t)(k0 + 64 + l31) * 8);
        kB1 = *(const uint4*)(Kb + (size_t)(k0 + 64 + 32 + l31) * 8);
    }

    f32x16 acc0 = {}, acc1 = {};
    float lsum = 0.0f;
    const f32x16 zf = {};

    for (int j = 0; j < ntiles; j += 2) {
        // ======== even tile j : compute set A from Vs[0] ========
        *(uint4*)(Vs[1] + ws) = vB;                      // tile j+1 (vmcnt counted)
        {
            const int jn = (j + 2 < ntiles) ? j + 2 : j; // clamped (harmless)
            vA = *(const uint4*)(vsrc + (size_t)jn * 64);
        }
        COMPUTE_TILE(0, kA0, kA1)
        {
            const int jn = (j + 2 < ntiles) ? j + 2 : j;
            if (hi == 0) {
                kA0 = *(const uint4*)(Kb + (size_t)(k0 + jn * 64 + l31) * 8);
                kA1 = *(const uint4*)(Kb + (size_t)(k0 + jn * 64 + 32 + l31) * 8);
            }
        }
        asm volatile("s_waitcnt lgkmcnt(0)" ::: "memory");
        __builtin_amdgcn_s_barrier();
        asm volatile("" ::: "memory");

        // ======== odd tile j+1 : compute set B from Vs[1] ========
        *(uint4*)(Vs[0] + ws) = vA;                      // tile j+2
        {
            const int jn = (j + 3 < ntiles) ? j + 3 : j + 1;
            vB = *(const uint4*)(vsrc + (size_t)jn * 64);
        }
        COMPUTE_TILE(1, kB0, kB1)
        {
            const int jn = (j + 3 < ntiles) ? j + 3 : j + 1;
            if (hi == 0) {
                kB0 = *(const uint4*)(Kb + (size_t)(k0 + jn * 64 + l31) * 8);
                kB1 = *(const uint4*)(Kb + (size_t)(k0 + jn * 64 + 32 + l31) * 8);
            }
        }
        asm volatile("s_waitcnt lgkmcnt(0)" ::: "memory");
        __builtin_amdgcn_s_barrier();
        asm volatile("" ::: "memory");
    }

    float ltot = lsum + __shfl_xor(lsum, 32);

    if (!FIN) {
        ushort_t* Pb = P + ((size_t)(s * Bb + b) * 64) * NN;
        #pragma unroll
        for (int reg = 0; reg < 16; reg++) {
            int m = reg >> 2, r = reg & 3;
            int ch0 = 4 * hi + 8 * m + r;
            Pb[(size_t)ch0 * NN + q0 + l31]        = (ushort_t)f2bf(acc0[reg]);
            Pb[(size_t)(ch0 + 32) * NN + q0 + l31] = (ushort_t)f2bf(acc1[reg]);
        }
        if (lane < 32)
            L[(size_t)(s * Bb + b) * NN + q0 + lane] = ltot;
    } else {
        const float gm = gamma[0];
        const float inv = 1.0f / ltot;
        #pragma unroll
        for (int reg = 0; reg < 16; reg++) {
            int m = reg >> 2, r = reg & 3;
            int ch0 = 4 * hi + 8 * m + r;
            size_t i0 = ((size_t)(b * 64 + ch0)) * NN + q0 + l31;
            size_t i1 = ((size_t)(b * 64 + ch0 + 32)) * NN + q0 + l31;
            out[i0] = x[i0] + gm * acc0[reg] * inv;
            out[i1] = x[i1] + gm * acc1[reg] * inv;
        }
    }
}

// ---------------- combine: thread = 8q x 8ch, vectorized ----------------------
__global__ __launch_bounds__(128) void combine_kernel(
    const ushort_t* __restrict__ P, const float* __restrict__ L,
    const float* __restrict__ x, const float* __restrict__ gamma,
    float* __restrict__ out, int nsplit)
{
    const int g = blockIdx.x * 128 + threadIdx.x;   // 32768 threads
    const int qo = g & 511;
    const int q0 = qo * 8;
    const int rest = g >> 9;                         // 0..63
    const int b  = rest & 7;
    const int cg = rest >> 3;                        // 0..7 -> ch0 = cg*8

    float ls[8];
    #pragma unroll
    for (int j = 0; j < 8; j++) ls[j] = 0.f;
    for (int s = 0; s < nsplit; s++) {
        const float* Lb = L + (size_t)(s * Bb + b) * NN + q0;
        float4 l0 = *(const float4*)(Lb);
        float4 l1 = *(const float4*)(Lb + 4);
        ls[0] += l0.x; ls[1] += l0.y; ls[2] += l0.z; ls[3] += l0.w;
        ls[4] += l1.x; ls[5] += l1.y; ls[6] += l1.z; ls[7] += l1.w;
    }

    float a[8][8];
    #pragma unroll
    for (int j = 0; j < 8; j++)
        #pragma unroll
        for (int k = 0; k < 8; k++) a[j][k] = 0.f;

    for (int s = 0; s < nsplit; s++) {
        #pragma unroll
        for (int j = 0; j < 8; j++) {
            const ushort_t* Pr = P + ((size_t)(s * Bb + b) * 64 + cg * 8 + j) * NN + q0;
            uint4 pv = *(const uint4*)Pr;
            uint_t u0 = pv.x, u1 = pv.y, u2 = pv.z, u3 = pv.w;
            a[j][0] += bitsf(u0 << 16); a[j][1] += bitsf(u0 & 0xFFFF0000u);
            a[j][2] += bitsf(u1 << 16); a[j][3] += bitsf(u1 & 0xFFFF0000u);
            a[j][4] += bitsf(u2 << 16); a[j][5] += bitsf(u2 & 0xFFFF0000u);
            a[j][6] += bitsf(u3 << 16); a[j][7] += bitsf(u3 & 0xFFFF0000u);
        }
    }

    float inv[8];
    #pragma unroll
    for (int k = 0; k < 8; k++) inv[k] = 1.0f / ls[k];
    const float gm = gamma[0];

    #pragma unroll
    for (int j = 0; j < 8; j++) {
        const size_t ro = ((size_t)(b * 64 + cg * 8 + j)) * NN + q0;
        float4 x0 = *(const float4*)(x + ro);
        float4 x1 = *(const float4*)(x + ro + 4);
        float4 o0, o1;
        o0.x = x0.x + gm * a[j][0] * inv[0];
        o0.y = x0.y + gm * a[j][1] * inv[1];
        o0.z = x0.z + gm * a[j][2] * inv[2];
        o0.w = x0.w + gm * a[j][3] * inv[3];
        o1.x = x1.x + gm * a[j][4] * inv[4];
        o1.y = x1.y + gm * a[j][5] * inv[5];
        o1.z = x1.z + gm * a[j][6] * inv[6];
        o1.w = x1.w + gm * a[j][7] * inv[7];
        *(float4*)(out + ro)     = o0;
        *(float4*)(out + ro + 4) = o1;
    }
}

extern "C" void kernel_launch(void* const* d_in, const int* in_sizes, int n_in,
                              void* d_out, int out_size, void* d_ws, size_t ws_size,
                              hipStream_t stream)
{
    const float* x       = (const float*)d_in[0];
    const float* theta_w = (const float*)d_in[1];
    const float* theta_b = (const float*)d_in[2];
    const float* phi_w   = (const float*)d_in[3];
    const float* phi_b   = (const float*)d_in[4];
    const float* g_w     = (const float*)d_in[5];
    const float* g_b     = (const float*)d_in[6];
    const float* gamma   = (const float*)d_in[7];
    float* out = (float*)d_out;

    // ws carve (all 16B aligned)
    char* p = (char*)d_ws;
    ushort_t* Qw  = (ushort_t*)p;  p += (size_t)Bb * NN * 8 * 2;        // 512 KB
    ushort_t* Kw  = (ushort_t*)p;  p += (size_t)Bb * NN * 8 * 2;        // 512 KB
    ushort_t* Vt  = (ushort_t*)p;  p += (size_t)Bb * 64 * NN * 2;       // 4 MB
    ushort_t* xbf = (ushort_t*)p;  p += (size_t)Bb * NN * 64 * 2;       // 4 MB
    ushort_t* Wbf = (ushort_t*)p;  p += 96 * 64 * 2;                    // 12 KB
    float*    biasf = (float*)p;   p += 96 * 4 + 128;                   // pad
    char*     pbase = p;
    const size_t base_bytes  = (size_t)(pbase - (char*)d_ws);
    const size_t split_bytes = (size_t)Bb * 64 * NN * 2 + (size_t)Bb * NN * 4;

    int ns = 1;
    const int cands[3] = {4, 2, 1};
    for (int i = 0; i < 3; i++)
        if (base_bytes + (size_t)cands[i] * split_bytes <= ws_size) { ns = cands[i]; break; }

    ushort_t* P = (ushort_t*)pbase;
    float*    L = (float*)(pbase + (size_t)ns * Bb * 64 * NN * 2);

    p1_kernel<<<513, 256, 0, stream>>>(x, theta_w, theta_b, phi_w, phi_b, g_w, g_b,
                                       xbf, Wbf, biasf);
    p2_kernel<<<Bb * 32, 256, 0, stream>>>(xbf, Wbf, biasf, Qw, Kw, Vt);

    if (ns > 1) {
        attn_kernel<0><<<ns * Bb * 16, 512, 0, stream>>>(Qw, Kw, Vt, P, L, ns,
                                                         nullptr, nullptr, nullptr);
        combine_kernel<<<256, 128, 0, stream>>>(P, L, x, gamma, out, ns);
    } else {
        attn_kernel<1><<<Bb * 16, 512, 0, stream>>>(Qw, Kw, Vt, P, L, 1,
                                                    x, gamma, out);
    }
}

// Round 10
// 53.409 us; speedup vs baseline: 1.4031x; 1.2203x over previous
//
#include <hip/hip_runtime.h>
#include <cstddef>
#include <cstdint>

// SelfAttention2d: B=8, C=64, N=4096, IC=8
// R10: R9 attn (raw barriers, static A/B prefetch, 8 waves) + K-dup (no exec-mask
// on K loads) + setprio around compute; combine restored to R4's 512x256 version.

#define Bb 8
#define Cc 64
#define NN 4096
#define IC 8
#define VSTR 72      // LDS V row stride (bf16 elems) = 144B (conflict-free, measured R8)
#define XSTR 72      // LDS Xs row stride in P2

typedef __attribute__((ext_vector_type(8)))  short bf16x8;
typedef __attribute__((ext_vector_type(16))) float f32x16;
typedef unsigned short ushort_t;
typedef unsigned int   uint_t;

#define LOG2E 1.4426950408889634f

static __device__ __forceinline__ uint_t f2bf(float x) {   // RNE
    union { float f; uint_t u; } v; v.f = x;
    uint_t r = v.u + 0x7FFF + ((v.u >> 16) & 1);
    return r >> 16;
}
static __device__ __forceinline__ float bf2f(ushort_t u) {
    union { uint_t u; float f; } v; v.u = ((uint_t)u) << 16;
    return v.f;
}
static __device__ __forceinline__ float fexp2(float x) {
#if __has_builtin(__builtin_amdgcn_exp2f)
    return __builtin_amdgcn_exp2f(x);
#else
    return exp2f(x);
#endif
}
static __device__ __forceinline__ uint_t fbits(float x) {
    union { float f; uint_t u; } v; v.f = x; return v.u;
}
// pack (lo=even, hi=odd) truncated bf16 pair via v_perm
static __device__ __forceinline__ uint_t packbf(float e, float o) {
#if __has_builtin(__builtin_amdgcn_perm)
    return __builtin_amdgcn_perm(fbits(o), fbits(e), 0x07060302u);
#else
    return (fbits(e) >> 16) | (fbits(o) & 0xFFFF0000u);
#endif
}

union U4B { uint4 u; bf16x8 v; };

// ---------------- P1: transpose x -> xbf [b][n][c] bf16; block 512: weights ----
__global__ __launch_bounds__(256) void p1_kernel(
    const float* __restrict__ x,
    const float* __restrict__ theta_w, const float* __restrict__ theta_b,
    const float* __restrict__ phi_w,   const float* __restrict__ phi_b,
    const float* __restrict__ g_w,     const float* __restrict__ g_b,
    ushort_t* __restrict__ xbf, ushort_t* __restrict__ Wbf, float* __restrict__ biasf)
{
    const int t = threadIdx.x;
    const int bid = blockIdx.x;
    if (bid < 512) {
        __shared__ float Xt[64 * 68];
        const int b  = bid >> 6;
        const int nt = (bid & 63) * 64;
        const int c = t >> 2, nsg = t & 3;
        const float* xs = x + ((size_t)(b * 64 + c)) * NN + nt + nsg * 16;
        #pragma unroll
        for (int i = 0; i < 4; i++) {
            float4 v = ((const float4*)xs)[i];
            *(float4*)(Xt + c * 68 + nsg * 16 + i * 4) = v;
        }
        __syncthreads();
        const int n = t & 63, cs = t >> 6;
        uint_t wv[8];
        #pragma unroll
        for (int i = 0; i < 8; i++) {
            float e0 = Xt[(cs * 16 + 2 * i + 0) * 68 + n];
            float e1 = Xt[(cs * 16 + 2 * i + 1) * 68 + n];
            wv[i] = f2bf(e0) | (f2bf(e1) << 16);
        }
        ushort_t* dst = xbf + ((size_t)(b * NN + nt + n)) * 64 + cs * 16;
        *(uint4*)dst       = make_uint4(wv[0], wv[1], wv[2], wv[3]);
        *(uint4*)(dst + 8) = make_uint4(wv[4], wv[5], wv[6], wv[7]);
    } else {
        // weights: Wbf[96][64] = [g(0-63); theta*log2e(64-71); phi(72-79); zero]
        for (int i = t; i < 96 * 64; i += 256) {
            int row = i >> 6, c = i & 63;
            float v;
            if (row < 64)      v = g_w[row * 64 + c];
            else if (row < 72) v = theta_w[(row - 64) * 64 + c] * LOG2E;
            else if (row < 80) v = phi_w[(row - 72) * 64 + c];
            else               v = 0.0f;
            Wbf[i] = (ushort_t)f2bf(v);
        }
        if (t < 96) {
            float bv = (t < 64) ? g_b[t]
                     : (t < 72) ? theta_b[t - 64] * LOG2E
                     : (t < 80) ? phi_b[t - 72] : 0.0f;
            biasf[t] = bv;
        }
    }
}

// ---------------- P2: projection GEMM: Y[96 x 128n] = W * X  per block ----------
__global__ __launch_bounds__(256) void p2_kernel(
    const ushort_t* __restrict__ xbf, const ushort_t* __restrict__ Wbf,
    const float* __restrict__ biasf,
    ushort_t* __restrict__ Qw, ushort_t* __restrict__ Kw, ushort_t* __restrict__ Vt)
{
    __shared__ ushort_t Xs[128 * XSTR];
    __shared__ float bs[96];

    const int t = threadIdx.x;
    const int lane = t & 63, w = t >> 6;
    const int l31 = lane & 31, hi = lane >> 5;
    const int b  = blockIdx.x >> 5;
    const int n0 = (blockIdx.x & 31) * 128;

    {
        const int n = t >> 1, h = t & 1;
        const ushort_t* src = xbf + ((size_t)(b * NN + n0 + n)) * 64 + h * 32;
        #pragma unroll
        for (int i = 0; i < 4; i++) {
            uint4 v = ((const uint4*)src)[i];
            *(uint4*)(Xs + n * XSTR + h * 32 + i * 8) = v;
        }
    }
    if (t < 96) bs[t] = biasf[t];
    __syncthreads();

    bf16x8 af[3][4];
    #pragma unroll
    for (int mt = 0; mt < 3; mt++)
        #pragma unroll
        for (int kc = 0; kc < 4; kc++)
            af[mt][kc] = *(const bf16x8*)(Wbf + (size_t)(mt * 32 + l31) * 64 + kc * 16 + hi * 8);

    f32x16 ac0 = {}, ac1 = {}, ac2 = {};
    #pragma unroll
    for (int kc = 0; kc < 4; kc++) {
        bf16x8 bv = *(const bf16x8*)(Xs + (w * 32 + l31) * XSTR + kc * 16 + hi * 8);
        ac0 = __builtin_amdgcn_mfma_f32_32x32x16_bf16(af[0][kc], bv, ac0, 0, 0, 0);
        ac1 = __builtin_amdgcn_mfma_f32_32x32x16_bf16(af[1][kc], bv, ac1, 0, 0, 0);
        ac2 = __builtin_amdgcn_mfma_f32_32x32x16_bf16(af[2][kc], bv, ac2, 0, 0, 0);
    }

    const int nw = n0 + w * 32;
    const int sig = ((l31 >> 3) & 1) * 16 + ((l31 >> 2) & 1) * 8 + ((l31 >> 4) & 1) * 4 + (l31 & 3);

    #pragma unroll
    for (int reg = 0; reg < 16; reg++) {
        int m = reg >> 2, r = reg & 3;
        {
            int ch = 4 * hi + 8 * m + r;
            float val = ac0[reg] + bs[ch];
            Vt[((size_t)(b * 64 + ch)) * NN + nw + sig] = (ushort_t)f2bf(val);
        }
        {
            int ch = 32 + 4 * hi + 8 * m + r;
            float val = ac1[reg] + bs[ch];
            Vt[((size_t)(b * 64 + ch)) * NN + nw + sig] = (ushort_t)f2bf(val);
        }
    }
    {
        float q0 = ac2[0] + bs[64 + 4 * hi + 0];
        float q1 = ac2[1] + bs[64 + 4 * hi + 1];
        float q2 = ac2[2] + bs[64 + 4 * hi + 2];
        float q3 = ac2[3] + bs[64 + 4 * hi + 3];
        uint2 qp = make_uint2(f2bf(q0) | (f2bf(q1) << 16), f2bf(q2) | (f2bf(q3) << 16));
        *(uint2*)(Qw + ((size_t)(b * NN) + nw + l31) * 8 + hi * 4) = qp;
        float p0 = ac2[4] + bs[72 + 4 * hi + 0];
        float p1 = ac2[5] + bs[72 + 4 * hi + 1];
        float p2 = ac2[6] + bs[72 + 4 * hi + 2];
        float p3 = ac2[7] + bs[72 + 4 * hi + 3];
        uint2 kp = make_uint2(f2bf(p0) | (f2bf(p1) << 16), f2bf(p2) | (f2bf(p3) << 16));
        *(uint2*)(Kw + ((size_t)(b * NN) + nw + l31) * 8 + hi * 4) = kp;
    }
}

// one 64-key tile of flash attn (R4 math). K operand duplicated across hi:
// A slots 8-15 hold finite K values, B (qf) slots 8-15 are zero -> contribute 0.
#define COMPUTE_TILE(CURBUF, KC0, KC1)                                                    \
    {                                                                                     \
        __builtin_amdgcn_s_setprio(1);                                                    \
        U4B ka0_, ka1_; ka0_.u = KC0; ka1_.u = KC1;                                       \
        f32x16 S0 = __builtin_amdgcn_mfma_f32_32x32x16_bf16(ka0_.v, qf, zf, 0, 0, 0);     \
        f32x16 S1 = __builtin_amdgcn_mfma_f32_32x32x16_bf16(ka1_.v, qf, zf, 0, 0, 0);     \
        float p0[16], p1[16];                                                             \
        _Pragma("unroll") for (int i = 0; i < 16; i++) p0[i] = fexp2(S0[i]);              \
        _Pragma("unroll") for (int i = 0; i < 16; i++) p1[i] = fexp2(S1[i]);              \
        _Pragma("unroll") for (int i = 0; i < 16; i++) { lsum += p0[i]; lsum += p1[i]; }  \
        uint_t pk0[8], pk1[8];                                                            \
        _Pragma("unroll") for (int m = 0; m < 4; m++) {                                   \
            _Pragma("unroll") for (int rp = 0; rp < 2; rp++) {                            \
                pk0[m * 2 + rp] = packbf(p0[m * 4 + 2 * rp], p0[m * 4 + 2 * rp + 1]);     \
                pk1[m * 2 + rp] = packbf(p1[m * 4 + 2 * rp], p1[m * 4 + 2 * rp + 1]);     \
            }                                                                             \
        }                                                                                 \
        _Pragma("unroll") for (int kf = 0; kf < 2; kf++) {                                \
            _Pragma("unroll") for (int c = 0; c < 2; c++) {                               \
                U4B bu;                                                                   \
                if (kf == 0) bu.u = make_uint4(pk0[c * 2], pk0[c * 2 + 1],                \
                                               pk0[(c + 2) * 2], pk0[(c + 2) * 2 + 1]);  \
                else         bu.u = make_uint4(pk1[c * 2], pk1[c * 2 + 1],                \
                                               pk1[(c + 2) * 2], pk1[(c + 2) * 2 + 1]);  \
                bf16x8 av0 = *(const bf16x8*)(Vs[CURBUF] + (0 * 32 + l31) * VSTR + kf * 32 + c * 16 + hi * 8); \
                bf16x8 av1 = *(const bf16x8*)(Vs[CURBUF] + (1 * 32 + l31) * VSTR + kf * 32 + c * 16 + hi * 8); \
                acc0 = __builtin_amdgcn_mfma_f32_32x32x16_bf16(av0, bu.v, acc0, 0, 0, 0); \
                acc1 = __builtin_amdgcn_mfma_f32_32x32x16_bf16(av1, bu.v, acc1, 0, 0, 0); \
            }                                                                             \
        }                                                                                 \
        __builtin_amdgcn_s_setprio(0);                                                    \
    }

// ---------------- attention: 8 waves, raw barriers, A/B prefetch sets ----------
template <int FIN>
__global__ __launch_bounds__(512, 3) void attn_kernel(
    const ushort_t* __restrict__ Qw, const ushort_t* __restrict__ Kw,
    const ushort_t* __restrict__ Vt,
    ushort_t* __restrict__ P, float* __restrict__ L, int nsplit,
    const float* __restrict__ x, const float* __restrict__ gamma,
    float* __restrict__ out)
{
    __shared__ ushort_t Vs[2][64 * VSTR];   // 18432 B

    const int t = threadIdx.x;
    const int lane = t & 63, w = t >> 6;          // 8 waves
    const int l31 = lane & 31, hi = lane >> 5;

    int bid = blockIdx.x;
    const int b  = bid & 7;                        // XCD-aligned batch
    const int qt = (bid >> 3) & 15;
    const int s  = bid >> 7;
    const int q0 = qt * 256 + w * 32;
    const int keys = NN / nsplit;
    const int k0 = s * keys;
    const int ntiles = keys / 64;                  // even for ns in {1,2,4}

    const ushort_t* Kb = Kw + (size_t)b * NN * 8;
    const ushort_t* Vb = Vt + (size_t)b * 64 * NN;

    bf16x8 qf = {};
    if (hi == 0)
        qf = *(const bf16x8*)(Qw + ((size_t)b * NN + q0 + l31) * 8);

    // V staging: 512 threads x 16B = 8KB tile
    const int vch = t >> 3, vsg = t & 7;
    const ushort_t* vsrc = Vb + (size_t)vch * NN + k0 + vsg * 8;
    const int ws = vch * VSTR + vsg * 8;

    uint4 vA, vB;
    uint4 kA0, kA1, kB0 = {}, kB1 = {};

    // prologue: tile 0 -> Vs[0]; then issue tile-1 loads (after the full drain)
    vA = *(const uint4*)(vsrc);
    kA0 = *(const uint4*)(Kb + (size_t)(k0 + l31) * 8);        // all lanes (dup)
    kA1 = *(const uint4*)(Kb + (size_t)(k0 + 32 + l31) * 8);
    *(uint4*)(Vs[0] + ws) = vA;
    __syncthreads();
    vB = *(const uint4*)(vsrc + 64);
    kB0 = *(const uint4*)(Kb + (size_t)(k0 + 64 + l31) * 8);
    kB1 = *(const uint4*)(Kb + (size_t)(k0 + 64 + 32 + l31) * 8);

    f32x16 acc0 = {}, acc1 = {};
    float lsum = 0.0f;
    const f32x16 zf = {};

    for (int j = 0; j < ntiles; j += 2) {
        // ======== even tile j : compute set A from Vs[0] ========
        *(uint4*)(Vs[1] + ws) = vB;                      // tile j+1 (vmcnt counted)
        {
            const int jn = (j + 2 < ntiles) ? j + 2 : j; // clamped (harmless)
            vA = *(const uint4*)(vsrc + (size_t)jn * 64);
        }
        COMPUTE_TILE(0, kA0, kA1)
        {
            const int jn = (j + 2 < ntiles) ? j + 2 : j;
            kA0 = *(const uint4*)(Kb + (size_t)(k0 + jn * 64 + l31) * 8);
            kA1 = *(const uint4*)(Kb + (size_t)(k0 + jn * 64 + 32 + l31) * 8);
        }
        asm volatile("s_waitcnt lgkmcnt(0)" ::: "memory");
        __builtin_amdgcn_s_barrier();
        asm volatile("" ::: "memory");

        // ======== odd tile j+1 : compute set B from Vs[1] ========
        *(uint4*)(Vs[0] + ws) = vA;                      // tile j+2
        {
            const int jn = (j + 3 < ntiles) ? j + 3 : j + 1;
            vB = *(const uint4*)(vsrc + (size_t)jn * 64);
        }
        COMPUTE_TILE(1, kB0, kB1)
        {
            const int jn = (j + 3 < ntiles) ? j + 3 : j + 1;
            kB0 = *(const uint4*)(Kb + (size_t)(k0 + jn * 64 + l31) * 8);
            kB1 = *(const uint4*)(Kb + (size_t)(k0 + jn * 64 + 32 + l31) * 8);
        }
        asm volatile("s_waitcnt lgkmcnt(0)" ::: "memory");
        __builtin_amdgcn_s_barrier();
        asm volatile("" ::: "memory");
    }

    float ltot = lsum + __shfl_xor(lsum, 32);

    if (!FIN) {
        ushort_t* Pb = P + ((size_t)(s * Bb + b) * 64) * NN;
        #pragma unroll
        for (int reg = 0; reg < 16; reg++) {
            int m = reg >> 2, r = reg & 3;
            int ch0 = 4 * hi + 8 * m + r;
            Pb[(size_t)ch0 * NN + q0 + l31]        = (ushort_t)f2bf(acc0[reg]);
            Pb[(size_t)(ch0 + 32) * NN + q0 + l31] = (ushort_t)f2bf(acc1[reg]);
        }
        if (lane < 32)
            L[(size_t)(s * Bb + b) * NN + q0 + lane] = ltot;
    } else {
        const float gm = gamma[0];
        const float inv = 1.0f / ltot;
        #pragma unroll
        for (int reg = 0; reg < 16; reg++) {
            int m = reg >> 2, r = reg & 3;
            int ch0 = 4 * hi + 8 * m + r;
            size_t i0 = ((size_t)(b * 64 + ch0)) * NN + q0 + l31;
            size_t i1 = ((size_t)(b * 64 + ch0 + 32)) * NN + q0 + l31;
            out[i0] = x[i0] + gm * acc0[reg] * inv;
            out[i1] = x[i1] + gm * acc1[reg] * inv;
        }
    }
}

// ---------------- combine (R4 version): 512 blocks x 256 threads ---------------
__global__ __launch_bounds__(256) void combine_kernel(
    const ushort_t* __restrict__ P, const float* __restrict__ L,
    const float* __restrict__ x, const float* __restrict__ gamma,
    float* __restrict__ out, int nsplit)
{
    const int T = blockIdx.x * 256 + threadIdx.x;
    const int q = T & (NN - 1);
    const int r2 = T >> 12;
    const int b = r2 & 7;
    const int cg = r2 >> 3;          // 0..3 (16 channels each)

    float ls = 0.0f;
    for (int s = 0; s < nsplit; s++)
        ls += L[(size_t)(s * Bb + b) * NN + q];

    float a[16];
    #pragma unroll
    for (int j = 0; j < 16; j++) a[j] = 0.0f;
    for (int s = 0; s < nsplit; s++) {
        const ushort_t* Pb = P + ((size_t)(s * Bb + b) * 64 + cg * 16) * NN + q;
        #pragma unroll
        for (int j = 0; j < 16; j++)
            a[j] += bf2f(Pb[(size_t)j * NN]);
    }

    const float inv = 1.0f / ls;
    const float gm = gamma[0];
    #pragma unroll
    for (int j = 0; j < 16; j++) {
        size_t idx = ((size_t)(b * 64 + cg * 16 + j)) * NN + q;
        out[idx] = x[idx] + gm * a[j] * inv;
    }
}

extern "C" void kernel_launch(void* const* d_in, const int* in_sizes, int n_in,
                              void* d_out, int out_size, void* d_ws, size_t ws_size,
                              hipStream_t stream)
{
    const float* x       = (const float*)d_in[0];
    const float* theta_w = (const float*)d_in[1];
    const float* theta_b = (const float*)d_in[2];
    const float* phi_w   = (const float*)d_in[3];
    const float* phi_b   = (const float*)d_in[4];
    const float* g_w     = (const float*)d_in[5];
    const float* g_b     = (const float*)d_in[6];
    const float* gamma   = (const float*)d_in[7];
    float* out = (float*)d_out;

    // ws carve (all 16B aligned)
    char* p = (char*)d_ws;
    ushort_t* Qw  = (ushort_t*)p;  p += (size_t)Bb * NN * 8 * 2;        // 512 KB
    ushort_t* Kw  = (ushort_t*)p;  p += (size_t)Bb * NN * 8 * 2;        // 512 KB
    ushort_t* Vt  = (ushort_t*)p;  p += (size_t)Bb * 64 * NN * 2;       // 4 MB
    ushort_t* xbf = (ushort_t*)p;  p += (size_t)Bb * NN * 64 * 2;       // 4 MB
    ushort_t* Wbf = (ushort_t*)p;  p += 96 * 64 * 2;                    // 12 KB
    float*    biasf = (float*)p;   p += 96 * 4 + 128;                   // pad
    char*     pbase = p;
    const size_t base_bytes  = (size_t)(pbase - (char*)d_ws);
    const size_t split_bytes = (size_t)Bb * 64 * NN * 2 + (size_t)Bb * NN * 4;

    int ns = 1;
    const int cands[3] = {4, 2, 1};
    for (int i = 0; i < 3; i++)
        if (base_bytes + (size_t)cands[i] * split_bytes <= ws_size) { ns = cands[i]; break; }

    ushort_t* P = (ushort_t*)pbase;
    float*    L = (float*)(pbase + (size_t)ns * Bb * 64 * NN * 2);

    p1_kernel<<<513, 256, 0, stream>>>(x, theta_w, theta_b, phi_w, phi_b, g_w, g_b,
                                       xbf, Wbf, biasf);
    p2_kernel<<<Bb * 32, 256, 0, stream>>>(xbf, Wbf, biasf, Qw, Kw, Vt);

    if (ns > 1) {
        attn_kernel<0><<<ns * Bb * 16, 512, 0, stream>>>(Qw, Kw, Vt, P, L, ns,
                                                         nullptr, nullptr, nullptr);
        combine_kernel<<<(Bb * NN * 4) / 256, 256, 0, stream>>>(P, L, x, gamma, out, ns);
    } else {
        attn_kernel<1><<<Bb * 16, 512, 0, stream>>>(Qw, Kw, Vt, P, L, 1,
                                                    x, gamma, out);
    }
}

// Round 11
// 51.686 us; speedup vs baseline: 1.4499x; 1.0334x over previous
//
#include <hip/hip_runtime.h>
#include <cstddef>
#include <cstdint>

// SelfAttention2d: B=8, C=64, N=4096, IC=8
// R11: p1 fused into p2 (x-transpose + weight convert in-block; p1 eliminated).
// Attn = R10 (raw barriers, static A/B prefetch, K-dup, setprio) with
// __launch_bounds__(512,4). Combine = R4's 512x256 version. ns<=4.

#define Bb 8
#define Cc 64
#define NN 4096
#define IC 8
#define VSTR 72      // LDS V row stride (bf16 elems) = 144B (conflict-free, measured R8)
#define XSTR 72      // LDS Xs row stride in P2

typedef __attribute__((ext_vector_type(8)))  short bf16x8;
typedef __attribute__((ext_vector_type(16))) float f32x16;
typedef unsigned short ushort_t;
typedef unsigned int   uint_t;

#define LOG2E 1.4426950408889634f

static __device__ __forceinline__ uint_t f2bf(float x) {   // RNE
    union { float f; uint_t u; } v; v.f = x;
    uint_t r = v.u + 0x7FFF + ((v.u >> 16) & 1);
    return r >> 16;
}
static __device__ __forceinline__ float bf2f(ushort_t u) {
    union { uint_t u; float f; } v; v.u = ((uint_t)u) << 16;
    return v.f;
}
static __device__ __forceinline__ float fexp2(float x) {
#if __has_builtin(__builtin_amdgcn_exp2f)
    return __builtin_amdgcn_exp2f(x);
#else
    return exp2f(x);
#endif
}
static __device__ __forceinline__ uint_t fbits(float x) {
    union { float f; uint_t u; } v; v.f = x; return v.u;
}
// pack (lo=even, hi=odd) truncated bf16 pair via v_perm
static __device__ __forceinline__ uint_t packbf(float e, float o) {
#if __has_builtin(__builtin_amdgcn_perm)
    return __builtin_amdgcn_perm(fbits(o), fbits(e), 0x07060302u);
#else
    return (fbits(e) >> 16) | (fbits(o) & 0xFFFF0000u);
#endif
}

union U4B { uint4 u; bf16x8 v; };

// ---------------- P2 (fused): x -> Q,K,V^T projections, one kernel ------------
// Per block: 128 pixels. Stage x f32 [c][n] -> transpose to bf16 Xs[n][c];
// convert weights in-block (L2 broadcast). Then 96x128 GEMM as before.
__global__ __launch_bounds__(256) void p2_kernel(
    const float* __restrict__ x,
    const float* __restrict__ theta_w, const float* __restrict__ theta_b,
    const float* __restrict__ phi_w,   const float* __restrict__ phi_b,
    const float* __restrict__ g_w,     const float* __restrict__ g_b,
    ushort_t* __restrict__ Qw, ushort_t* __restrict__ Kw, ushort_t* __restrict__ Vt)
{
    __shared__ float    Xt[64 * 132];      // f32 [c][n], pad 4 -> 33.8 KB
    __shared__ ushort_t Xs[128 * XSTR];    // bf16 [n][c]      -> 18.4 KB
    __shared__ ushort_t Wl[96 * 64];       // bf16 weights     -> 12.3 KB
    __shared__ float    bs[96];

    const int t = threadIdx.x;
    const int lane = t & 63, w = t >> 6;
    const int l31 = lane & 31, hi = lane >> 5;
    const int b  = blockIdx.x >> 5;
    const int n0 = (blockIdx.x & 31) * 128;

    // ---- stage x tile: thread (c = t>>2, seg = t&3) loads 32 consecutive f32
    {
        const int c = t >> 2, seg = t & 3;
        const float* xs = x + ((size_t)(b * 64 + c)) * NN + n0 + seg * 32;
        #pragma unroll
        for (int i = 0; i < 8; i++) {
            float4 v = ((const float4*)xs)[i];
            *(float4*)(Xt + c * 132 + seg * 32 + i * 4) = v;
        }
    }
    // ---- weights: [g(0-63); theta*log2e(64-71); phi(72-79); zero(80-95)]
    for (int i = t; i < 96 * 64; i += 256) {
        int row = i >> 6, c = i & 63;
        float v;
        if (row < 64)      v = g_w[i];
        else if (row < 72) v = theta_w[(row - 64) * 64 + c] * LOG2E;
        else if (row < 80) v = phi_w[(row - 72) * 64 + c];
        else               v = 0.0f;
        Wl[i] = (ushort_t)f2bf(v);
    }
    if (t < 96) {
        bs[t] = (t < 64) ? g_b[t]
              : (t < 72) ? theta_b[t - 64] * LOG2E
              : (t < 80) ? phi_b[t - 72] : 0.0f;
    }
    __syncthreads();

    // ---- transpose to Xs[n][c] bf16: thread (n = t&127, half = t>>7)
    // column reads are lane-consecutive in n -> conflict-free
    {
        const int n = t & 127, half = t >> 7;
        uint_t wv[16];
        #pragma unroll
        for (int i = 0; i < 16; i++) {
            float e0 = Xt[(half * 32 + 2 * i + 0) * 132 + n];
            float e1 = Xt[(half * 32 + 2 * i + 1) * 132 + n];
            wv[i] = f2bf(e0) | (f2bf(e1) << 16);
        }
        #pragma unroll
        for (int i = 0; i < 4; i++)
            *(uint4*)(Xs + n * XSTR + half * 32 + i * 8) =
                make_uint4(wv[4 * i], wv[4 * i + 1], wv[4 * i + 2], wv[4 * i + 3]);
    }
    __syncthreads();

    // ---- GEMM: Y[96 x 128] = W * Xs ----
    bf16x8 af[3][4];
    #pragma unroll
    for (int mt = 0; mt < 3; mt++)
        #pragma unroll
        for (int kc = 0; kc < 4; kc++)
            af[mt][kc] = *(const bf16x8*)(Wl + (size_t)(mt * 32 + l31) * 64 + kc * 16 + hi * 8);

    f32x16 ac0 = {}, ac1 = {}, ac2 = {};
    #pragma unroll
    for (int kc = 0; kc < 4; kc++) {
        bf16x8 bv = *(const bf16x8*)(Xs + (w * 32 + l31) * XSTR + kc * 16 + hi * 8);
        ac0 = __builtin_amdgcn_mfma_f32_32x32x16_bf16(af[0][kc], bv, ac0, 0, 0, 0);
        ac1 = __builtin_amdgcn_mfma_f32_32x32x16_bf16(af[1][kc], bv, ac1, 0, 0, 0);
        ac2 = __builtin_amdgcn_mfma_f32_32x32x16_bf16(af[2][kc], bv, ac2, 0, 0, 0);
    }

    const int nw = n0 + w * 32;
    const int sig = ((l31 >> 3) & 1) * 16 + ((l31 >> 2) & 1) * 8 + ((l31 >> 4) & 1) * 4 + (l31 & 3);

    #pragma unroll
    for (int reg = 0; reg < 16; reg++) {
        int m = reg >> 2, r = reg & 3;
        {
            int ch = 4 * hi + 8 * m + r;
            float val = ac0[reg] + bs[ch];
            Vt[((size_t)(b * 64 + ch)) * NN + nw + sig] = (ushort_t)f2bf(val);
        }
        {
            int ch = 32 + 4 * hi + 8 * m + r;
            float val = ac1[reg] + bs[ch];
            Vt[((size_t)(b * 64 + ch)) * NN + nw + sig] = (ushort_t)f2bf(val);
        }
    }
    {
        float q0 = ac2[0] + bs[64 + 4 * hi + 0];
        float q1 = ac2[1] + bs[64 + 4 * hi + 1];
        float q2 = ac2[2] + bs[64 + 4 * hi + 2];
        float q3 = ac2[3] + bs[64 + 4 * hi + 3];
        uint2 qp = make_uint2(f2bf(q0) | (f2bf(q1) << 16), f2bf(q2) | (f2bf(q3) << 16));
        *(uint2*)(Qw + ((size_t)(b * NN) + nw + l31) * 8 + hi * 4) = qp;
        float p0 = ac2[4] + bs[72 + 4 * hi + 0];
        float p1 = ac2[5] + bs[72 + 4 * hi + 1];
        float p2 = ac2[6] + bs[72 + 4 * hi + 2];
        float p3 = ac2[7] + bs[72 + 4 * hi + 3];
        uint2 kp = make_uint2(f2bf(p0) | (f2bf(p1) << 16), f2bf(p2) | (f2bf(p3) << 16));
        *(uint2*)(Kw + ((size_t)(b * NN) + nw + l31) * 8 + hi * 4) = kp;
    }
}

// one 64-key tile of flash attn (R4 math). K operand duplicated across hi:
// A slots 8-15 hold finite K values, B (qf) slots 8-15 are zero -> contribute 0.
#define COMPUTE_TILE(CURBUF, KC0, KC1)                                                    \
    {                                                                                     \
        __builtin_amdgcn_s_setprio(1);                                                    \
        U4B ka0_, ka1_; ka0_.u = KC0; ka1_.u = KC1;                                       \
        f32x16 S0 = __builtin_amdgcn_mfma_f32_32x32x16_bf16(ka0_.v, qf, zf, 0, 0, 0);     \
        f32x16 S1 = __builtin_amdgcn_mfma_f32_32x32x16_bf16(ka1_.v, qf, zf, 0, 0, 0);     \
        float p0[16], p1[16];                                                             \
        _Pragma("unroll") for (int i = 0; i < 16; i++) p0[i] = fexp2(S0[i]);              \
        _Pragma("unroll") for (int i = 0; i < 16; i++) p1[i] = fexp2(S1[i]);              \
        _Pragma("unroll") for (int i = 0; i < 16; i++) { lsum += p0[i]; lsum += p1[i]; }  \
        uint_t pk0[8], pk1[8];                                                            \
        _Pragma("unroll") for (int m = 0; m < 4; m++) {                                   \
            _Pragma("unroll") for (int rp = 0; rp < 2; rp++) {                            \
                pk0[m * 2 + rp] = packbf(p0[m * 4 + 2 * rp], p0[m * 4 + 2 * rp + 1]);     \
                pk1[m * 2 + rp] = packbf(p1[m * 4 + 2 * rp], p1[m * 4 + 2 * rp + 1]);     \
            }                                                                             \
        }                                                                                 \
        _Pragma("unroll") for (int kf = 0; kf < 2; kf++) {                                \
            _Pragma("unroll") for (int c = 0; c < 2; c++) {                               \
                U4B bu;                                                                   \
                if (kf == 0) bu.u = make_uint4(pk0[c * 2], pk0[c * 2 + 1],                \
                                               pk0[(c + 2) * 2], pk0[(c + 2) * 2 + 1]);  \
                else         bu.u = make_uint4(pk1[c * 2], pk1[c * 2 + 1],                \
                                               pk1[(c + 2) * 2], pk1[(c + 2) * 2 + 1]);  \
                bf16x8 av0 = *(const bf16x8*)(Vs[CURBUF] + (0 * 32 + l31) * VSTR + kf * 32 + c * 16 + hi * 8); \
                bf16x8 av1 = *(const bf16x8*)(Vs[CURBUF] + (1 * 32 + l31) * VSTR + kf * 32 + c * 16 + hi * 8); \
                acc0 = __builtin_amdgcn_mfma_f32_32x32x16_bf16(av0, bu.v, acc0, 0, 0, 0); \
                acc1 = __builtin_amdgcn_mfma_f32_32x32x16_bf16(av1, bu.v, acc1, 0, 0, 0); \
            }                                                                             \
        }                                                                                 \
        __builtin_amdgcn_s_setprio(0);                                                    \
    }

// ---------------- attention: 8 waves, raw barriers, A/B prefetch sets ----------
template <int FIN>
__global__ __launch_bounds__(512, 4) void attn_kernel(
    const ushort_t* __restrict__ Qw, const ushort_t* __restrict__ Kw,
    const ushort_t* __restrict__ Vt,
    ushort_t* __restrict__ P, float* __restrict__ L, int nsplit,
    const float* __restrict__ x, const float* __restrict__ gamma,
    float* __restrict__ out)
{
    __shared__ ushort_t Vs[2][64 * VSTR];   // 18432 B

    const int t = threadIdx.x;
    const int lane = t & 63, w = t >> 6;          // 8 waves
    const int l31 = lane & 31, hi = lane >> 5;

    int bid = blockIdx.x;
    const int b  = bid & 7;                        // XCD-aligned batch
    const int qt = (bid >> 3) & 15;
    const int s  = bid >> 7;
    const int q0 = qt * 256 + w * 32;
    const int keys = NN / nsplit;
    const int k0 = s * keys;
    const int ntiles = keys / 64;                  // even for ns in {1,2,4}

    const ushort_t* Kb = Kw + (size_t)b * NN * 8;
    const ushort_t* Vb = Vt + (size_t)b * 64 * NN;

    bf16x8 qf = {};
    if (hi == 0)
        qf = *(const bf16x8*)(Qw + ((size_t)b * NN + q0 + l31) * 8);

    // V staging: 512 threads x 16B = 8KB tile
    const int vch = t >> 3, vsg = t & 7;
    const ushort_t* vsrc = Vb + (size_t)vch * NN + k0 + vsg * 8;
    const int ws = vch * VSTR + vsg * 8;

    uint4 vA, vB;
    uint4 kA0, kA1, kB0 = {}, kB1 = {};

    // prologue: tile 0 -> Vs[0]; then issue tile-1 loads (after the full drain)
    vA = *(const uint4*)(vsrc);
    kA0 = *(const uint4*)(Kb + (size_t)(k0 + l31) * 8);        // all lanes (dup)
    kA1 = *(const uint4*)(Kb + (size_t)(k0 + 32 + l31) * 8);
    *(uint4*)(Vs[0] + ws) = vA;
    __syncthreads();
    vB = *(const uint4*)(vsrc + 64);
    kB0 = *(const uint4*)(Kb + (size_t)(k0 + 64 + l31) * 8);
    kB1 = *(const uint4*)(Kb + (size_t)(k0 + 64 + 32 + l31) * 8);

    f32x16 acc0 = {}, acc1 = {};
    float lsum = 0.0f;
    const f32x16 zf = {};

    for (int j = 0; j < ntiles; j += 2) {
        // ======== even tile j : compute set A from Vs[0] ========
        *(uint4*)(Vs[1] + ws) = vB;                      // tile j+1 (vmcnt counted)
        {
            const int jn = (j + 2 < ntiles) ? j + 2 : j; // clamped (harmless)
            vA = *(const uint4*)(vsrc + (size_t)jn * 64);
        }
        COMPUTE_TILE(0, kA0, kA1)
        {
            const int jn = (j + 2 < ntiles) ? j + 2 : j;
            kA0 = *(const uint4*)(Kb + (size_t)(k0 + jn * 64 + l31) * 8);
            kA1 = *(const uint4*)(Kb + (size_t)(k0 + jn * 64 + 32 + l31) * 8);
        }
        asm volatile("s_waitcnt lgkmcnt(0)" ::: "memory");
        __builtin_amdgcn_s_barrier();
        asm volatile("" ::: "memory");

        // ======== odd tile j+1 : compute set B from Vs[1] ========
        *(uint4*)(Vs[0] + ws) = vA;                      // tile j+2
        {
            const int jn = (j + 3 < ntiles) ? j + 3 : j + 1;
            vB = *(const uint4*)(vsrc + (size_t)jn * 64);
        }
        COMPUTE_TILE(1, kB0, kB1)
        {
            const int jn = (j + 3 < ntiles) ? j + 3 : j + 1;
            kB0 = *(const uint4*)(Kb + (size_t)(k0 + jn * 64 + l31) * 8);
            kB1 = *(const uint4*)(Kb + (size_t)(k0 + jn * 64 + 32 + l31) * 8);
        }
        asm volatile("s_waitcnt lgkmcnt(0)" ::: "memory");
        __builtin_amdgcn_s_barrier();
        asm volatile("" ::: "memory");
    }

    float ltot = lsum + __shfl_xor(lsum, 32);

    if (!FIN) {
        ushort_t* Pb = P + ((size_t)(s * Bb + b) * 64) * NN;
        #pragma unroll
        for (int reg = 0; reg < 16; reg++) {
            int m = reg >> 2, r = reg & 3;
            int ch0 = 4 * hi + 8 * m + r;
            Pb[(size_t)ch0 * NN + q0 + l31]        = (ushort_t)f2bf(acc0[reg]);
            Pb[(size_t)(ch0 + 32) * NN + q0 + l31] = (ushort_t)f2bf(acc1[reg]);
        }
        if (lane < 32)
            L[(size_t)(s * Bb + b) * NN + q0 + lane] = ltot;
    } else {
        const float gm = gamma[0];
        const float inv = 1.0f / ltot;
        #pragma unroll
        for (int reg = 0; reg < 16; reg++) {
            int m = reg >> 2, r = reg & 3;
            int ch0 = 4 * hi + 8 * m + r;
            size_t i0 = ((size_t)(b * 64 + ch0)) * NN + q0 + l31;
            size_t i1 = ((size_t)(b * 64 + ch0 + 32)) * NN + q0 + l31;
            out[i0] = x[i0] + gm * acc0[reg] * inv;
            out[i1] = x[i1] + gm * acc1[reg] * inv;
        }
    }
}

// ---------------- combine (R4 version): 512 blocks x 256 threads ---------------
__global__ __launch_bounds__(256) void combine_kernel(
    const ushort_t* __restrict__ P, const float* __restrict__ L,
    const float* __restrict__ x, const float* __restrict__ gamma,
    float* __restrict__ out, int nsplit)
{
    const int T = blockIdx.x * 256 + threadIdx.x;
    const int q = T & (NN - 1);
    const int r2 = T >> 12;
    const int b = r2 & 7;
    const int cg = r2 >> 3;          // 0..3 (16 channels each)

    float ls = 0.0f;
    for (int s = 0; s < nsplit; s++)
        ls += L[(size_t)(s * Bb + b) * NN + q];

    float a[16];
    #pragma unroll
    for (int j = 0; j < 16; j++) a[j] = 0.0f;
    for (int s = 0; s < nsplit; s++) {
        const ushort_t* Pb = P + ((size_t)(s * Bb + b) * 64 + cg * 16) * NN + q;
        #pragma unroll
        for (int j = 0; j < 16; j++)
            a[j] += bf2f(Pb[(size_t)j * NN]);
    }

    const float inv = 1.0f / ls;
    const float gm = gamma[0];
    #pragma unroll
    for (int j = 0; j < 16; j++) {
        size_t idx = ((size_t)(b * 64 + cg * 16 + j)) * NN + q;
        out[idx] = x[idx] + gm * a[j] * inv;
    }
}

extern "C" void kernel_launch(void* const* d_in, const int* in_sizes, int n_in,
                              void* d_out, int out_size, void* d_ws, size_t ws_size,
                              hipStream_t stream)
{
    const float* x       = (const float*)d_in[0];
    const float* theta_w = (const float*)d_in[1];
    const float* theta_b = (const float*)d_in[2];
    const float* phi_w   = (const float*)d_in[3];
    const float* phi_b   = (const float*)d_in[4];
    const float* g_w     = (const float*)d_in[5];
    const float* g_b     = (const float*)d_in[6];
    const float* gamma   = (const float*)d_in[7];
    float* out = (float*)d_out;

    // ws carve (all 16B aligned)
    char* p = (char*)d_ws;
    ushort_t* Qw  = (ushort_t*)p;  p += (size_t)Bb * NN * 8 * 2;        // 512 KB
    ushort_t* Kw  = (ushort_t*)p;  p += (size_t)Bb * NN * 8 * 2;        // 512 KB
    ushort_t* Vt  = (ushort_t*)p;  p += (size_t)Bb * 64 * NN * 2;       // 4 MB
    char*     pbase = p;
    const size_t base_bytes  = (size_t)(pbase - (char*)d_ws);
    const size_t split_bytes = (size_t)Bb * 64 * NN * 2 + (size_t)Bb * NN * 4;

    int ns = 1;
    const int cands[3] = {4, 2, 1};
    for (int i = 0; i < 3; i++)
        if (base_bytes + (size_t)cands[i] * split_bytes <= ws_size) { ns = cands[i]; break; }

    ushort_t* P = (ushort_t*)pbase;
    float*    L = (float*)(pbase + (size_t)ns * Bb * 64 * NN * 2);

    p2_kernel<<<Bb * 32, 256, 0, stream>>>(x, theta_w, theta_b, phi_w, phi_b,
                                           g_w, g_b, Qw, Kw, Vt);

    if (ns > 1) {
        attn_kernel<0><<<ns * Bb * 16, 512, 0, stream>>>(Qw, Kw, Vt, P, L, ns,
                                                         nullptr, nullptr, nullptr);
        combine_kernel<<<(Bb * NN * 4) / 256, 256, 0, stream>>>(P, L, x, gamma, out, ns);
    } else {
        attn_kernel<1><<<Bb * 16, 512, 0, stream>>>(Qw, Kw, Vt, P, L, 1,
                                                    x, gamma, out);
    }
}